// Round 1
// baseline (241.986 us; speedup 1.0000x reference)
//
#include <hip/hip_runtime.h>
#include <cstddef>

#define NN 1024
#define HF 128
#define DE_ 32
#define SLOPE 0.2f
#define EPSV 1e-5f
#define ETILE 64   // edges staged to LDS per tile in attn phase A
#define MCAP 320   // max live neighbors per row (dist: 51 +/- 7; 320 = 38 sigma)

// ---------------- Kernel 1: node projections (4 nodes/block) --------------
// Also zeroes the BN accumulator block (block 0) for this iteration.
__global__ __launch_bounds__(256) void proj_kernel(
    const float* __restrict__ x, const float* __restrict__ W_proj,
    const float* __restrict__ W_skip, const float* __restrict__ a_src,
    const float* __restrict__ a_tgt, float* __restrict__ nproj,
    float* __restrict__ skip, float* __restrict__ s_src,
    float* __restrict__ s_tgt, float* __restrict__ bn_sums)
{
  const int b = blockIdx.x, t = threadIdx.x;     // block handles nodes 4b..4b+3
  if (b == 0) bn_sums[t] = 0.f;                  // 256 floats: sum[128], sum2[128]
  __shared__ float xs[4 * 128];
  xs[t] = x[(size_t)b * 512 + t];
  xs[t + 256] = x[(size_t)b * 512 + t + 256];
  __syncthreads();
  const int sel = t >> 7;                        // 0: W_proj/nproj, 1: W_skip/skip
  const float* W = sel ? W_skip : W_proj;        // wave-uniform
  const int c = t & 127;
  float acc0 = 0.f, acc1 = 0.f, acc2 = 0.f, acc3 = 0.f;
#pragma unroll 8
  for (int k = 0; k < 128; ++k) {
    const float w = W[k * 128 + c];
    acc0 = fmaf(xs[k], w, acc0);
    acc1 = fmaf(xs[128 + k], w, acc1);
    acc2 = fmaf(xs[256 + k], w, acc2);
    acc3 = fmaf(xs[384 + k], w, acc3);
  }
  float* dst = sel ? skip : nproj;
  dst[(size_t)(4 * b + 0) * 128 + c] = acc0;
  dst[(size_t)(4 * b + 1) * 128 + c] = acc1;
  dst[(size_t)(4 * b + 2) * 128 + c] = acc2;
  dst[(size_t)(4 * b + 3) * 128 + c] = acc3;
  if (sel == 0) {                                // logits from nproj accs
    const float as = a_src[c], at = a_tgt[c];
    const int h = c >> 5;
    float accs[4] = {acc0, acc1, acc2, acc3};
#pragma unroll
    for (int n = 0; n < 4; ++n) {
      float vs = accs[n] * as, vt = accs[n] * at;
#pragma unroll
      for (int off = 16; off; off >>= 1) {
        vs += __shfl_down(vs, off, 32);
        vt += __shfl_down(vt, off, 32);
      }
      if ((c & 31) == 0) {
        s_src[(4 * b + n) * 4 + h] = vs;
        s_tgt[(4 * b + n) * 4 + h] = vt;
      }
    }
  }
}

// ---------------- Kernel 2: sparse fused attention -----------------------
// One block (256 thr) per target row i. Masked entries are exactly 0 after
// softmax (exp(-1e9-max) underflows), so only conn==0 neighbors matter.
// Epilogue also accumulates per-channel BN sums via global fp32 atomics.
__global__ __launch_bounds__(256) void attn_kernel(
    const float* __restrict__ e,      // [N,N,32]
    const float* __restrict__ conn,   // [N,N]
    const float* __restrict__ W_edge, // [32,128]
    const float* __restrict__ b_edge, // [128]
    const float* __restrict__ a_edge, // [128]
    const float* __restrict__ s_src,  // [N,4]
    const float* __restrict__ s_tgt,  // [N,4]
    const float* __restrict__ nproj,  // [N,128]
    const float* __restrict__ skip,   // [N,128]
    float* __restrict__ out_pre,      // [N,128]
    float* __restrict__ bn_sums)      // [256]: sum[128], sum2[128]
{
  const int i = blockIdx.x, t = threadIdx.x;
  __shared__ unsigned short nbr[NN];
  __shared__ float sc[MCAP * 4];          // scores -> attn weights, [n][h]
  __shared__ float ebuf[ETILE * 32];      // staged e-rows for current tile
  __shared__ float partial[256];
  __shared__ int cnt;

  const int c = t & 127;                  // output channel
  const int h = c >> 5;                   // head
  const int half = t >> 7;                // 0/1: edge-interleave group

  float Wc[DE_];                          // W_edge column c in registers
#pragma unroll
  for (int k = 0; k < DE_; ++k) Wc[k] = W_edge[k * 128 + c];
  const float aec = a_edge[c];
  const float bec = b_edge[c];
  const float ssi = s_src[i * 4 + h];

  if (t == 0) cnt = 0;
  __syncthreads();
  // --- compact live-neighbor list (order-free; only perturbs fp assoc.) ---
  {
    const float4 cv = ((const float4*)(conn + (size_t)i * NN))[t];
    const int jb = t << 2;
    if (cv.x > -0.5f) { int p = atomicAdd(&cnt, 1); nbr[p] = (unsigned short)(jb + 0); }
    if (cv.y > -0.5f) { int p = atomicAdd(&cnt, 1); nbr[p] = (unsigned short)(jb + 1); }
    if (cv.z > -0.5f) { int p = atomicAdd(&cnt, 1); nbr[p] = (unsigned short)(jb + 2); }
    if (cv.w > -0.5f) { int p = atomicAdd(&cnt, 1); nbr[p] = (unsigned short)(jb + 3); }
  }
  __syncthreads();
  const int M = min(cnt, MCAP);

  // --- phase A: per-edge scores, LDS-staged tiles -----------------------
  for (int base = 0; base < M; base += ETILE) {
    const int mT = min(ETILE, M - base);
    // cooperative stage: mT rows x 8 float4, all loads in flight at once
    for (int q = t; q < mT * 8; q += 256) {
      const int n = q >> 3, part = q & 7;
      const int j = nbr[base + n];
      ((float4*)ebuf)[q] =
          ((const float4*)(e + ((size_t)i << 15) + ((size_t)j << 5)))[part];
    }
    __syncthreads();
    for (int n = half; n < mT; n += 2) {
      const float4* eb4 = (const float4*)(ebuf + n * 32);  // wave-uniform addr
      float acc = bec;
#pragma unroll
      for (int q = 0; q < 8; ++q) {
        float4 v = eb4[q];
        acc = fmaf(v.x, Wc[4 * q + 0], acc);
        acc = fmaf(v.y, Wc[4 * q + 1], acc);
        acc = fmaf(v.z, Wc[4 * q + 2], acc);
        acc = fmaf(v.w, Wc[4 * q + 3], acc);
      }
      acc = acc > 0.f ? acc : SLOPE * acc;        // leaky on eproj
      float contrib = acc * aec;
#pragma unroll
      for (int off = 16; off; off >>= 1) contrib += __shfl_down(contrib, off, 32);
      if ((c & 31) == 0) {
        const int j = nbr[base + n];
        float sco = ssi + s_tgt[(size_t)j * 4 + h] + contrib;
        sco = sco > 0.f ? sco : SLOPE * sco;      // leaky on logits
        sc[(base + n) * 4 + h] = sco;
      }
    }
    __syncthreads();
  }

  // --- phase B: per-head softmax (one wave per head) --------------------
  {
    const int hh = t >> 6;
    const int lane = t & 63;
    float m = -1e30f;
    for (int n = lane; n < M; n += 64) m = fmaxf(m, sc[n * 4 + hh]);
#pragma unroll
    for (int off = 32; off; off >>= 1) m = fmaxf(m, __shfl_down(m, off, 64));
    m = __shfl(m, 0, 64);
    float s = 0.f;
    for (int n = lane; n < M; n += 64) s += __expf(sc[n * 4 + hh] - m);
#pragma unroll
    for (int off = 32; off; off >>= 1) s += __shfl_down(s, off, 64);
    s = __shfl(s, 0, 64);
    const float inv = 1.f / s;
    for (int n = lane; n < M; n += 64)
      sc[n * 4 + hh] = __expf(sc[n * 4 + hh] - m) * inv;
  }
  __syncthreads();

  // --- phase C: aggregate attn * nproj + skip; feed BN stats ------------
  float accum = 0.f;
  for (int n = half; n < M; n += 2) {
    const int j = nbr[n];
    accum = fmaf(sc[n * 4 + h], nproj[(size_t)j * 128 + c], accum);
  }
  partial[t] = accum;
  __syncthreads();
  if (t < 128) {
    float tot = partial[t] + partial[t + 128] + skip[(size_t)i * 128 + t];
    out_pre[(size_t)i * 128 + t] = tot;
    atomicAdd(bn_sums + t, tot);                  // per-channel sum
    atomicAdd(bn_sums + 128 + t, tot * tot);      // per-channel sum of squares
  }
}

// ---------------- Kernel 3: BN apply + bias + ELU (coalesced float4) ------
__global__ __launch_bounds__(256) void bn_apply_kernel(
    const float* __restrict__ out_pre, const float* __restrict__ bn_sums,
    const float* __restrict__ gamma, const float* __restrict__ beta,
    const float* __restrict__ bias, float* __restrict__ out)
{
  const int idx4 = blockIdx.x * 256 + threadIdx.x;   // 0..32767, = r*32 + c4/4
  const int c4 = (idx4 & 31) << 2;
  const float4 v = ((const float4*)out_pre)[idx4];
  const float r[4] = {v.x, v.y, v.z, v.w};
  float o[4];
#pragma unroll
  for (int k = 0; k < 4; ++k) {
    const int c = c4 + k;
    const float mu = bn_sums[c] * (1.f / 1024.f);
    const float var = bn_sums[128 + c] * (1.f / 1024.f) - mu * mu;
    const float rstd = rsqrtf(var + EPSV);
    const float g = gamma[c] * rstd;
    const float bb = beta[c] + bias[c] - mu * g;
    const float y = r[k] * g + bb;
    o[k] = y > 0.f ? y : expm1f(y);
  }
  ((float4*)out)[idx4] = make_float4(o[0], o[1], o[2], o[3]);
}

// ---------------- Launch ---------------------------------------------------
extern "C" void kernel_launch(void* const* d_in, const int* in_sizes, int n_in,
                              void* d_out, int out_size, void* d_ws,
                              size_t ws_size, hipStream_t stream)
{
  const float* x      = (const float*)d_in[0];
  const float* e      = (const float*)d_in[1];
  const float* conn   = (const float*)d_in[2];
  const float* W_proj = (const float*)d_in[3];
  const float* W_edge = (const float*)d_in[4];
  const float* b_edge = (const float*)d_in[5];
  const float* a_src  = (const float*)d_in[6];
  const float* a_tgt  = (const float*)d_in[7];
  const float* a_edge = (const float*)d_in[8];
  const float* W_skip = (const float*)d_in[9];
  const float* gamma  = (const float*)d_in[10];
  const float* beta   = (const float*)d_in[11];
  const float* bias   = (const float*)d_in[12];

  float* nproj   = (float*)d_ws;
  float* skip    = nproj + (size_t)NN * HF;
  float* out_pre = skip + (size_t)NN * HF;
  float* s_src   = out_pre + (size_t)NN * HF;
  float* s_tgt   = s_src + (size_t)NN * 4;
  float* bn_sums = s_tgt + (size_t)NN * 4;   // 256 floats: sum[128], sum2[128]

  proj_kernel<<<NN / 4, 256, 0, stream>>>(x, W_proj, W_skip, a_src, a_tgt,
                                          nproj, skip, s_src, s_tgt, bn_sums);
  attn_kernel<<<NN, 256, 0, stream>>>(e, conn, W_edge, b_edge, a_edge,
                                      s_src, s_tgt, nproj, skip, out_pre,
                                      bn_sums);
  bn_apply_kernel<<<(NN * HF) / (256 * 4), 256, 0, stream>>>(
      out_pre, bn_sums, gamma, beta, bias, (float*)d_out);
}

// Round 2
// 232.665 us; speedup vs baseline: 1.0401x; 1.0401x over previous
//
#include <hip/hip_runtime.h>
#include <cstddef>

#define NN 1024
#define HF 128
#define DE_ 32
#define SLOPE 0.2f
#define EPSV 1e-5f
#define ETILE 64   // edges staged to LDS per tile in attn phase A
#define MCAP 320   // max live neighbors per row (dist: 51 +/- 7; 320 = 38 sigma)

// ---------------- Kernel 1: node projections (4 nodes/block) --------------
// Also zeroes the BN accumulator block (block 0) for this iteration.
__global__ __launch_bounds__(256) void proj_kernel(
    const float* __restrict__ x, const float* __restrict__ W_proj,
    const float* __restrict__ W_skip, const float* __restrict__ a_src,
    const float* __restrict__ a_tgt, float* __restrict__ nproj,
    float* __restrict__ skip, float* __restrict__ s_src,
    float* __restrict__ s_tgt, float* __restrict__ bn_sums)
{
  const int b = blockIdx.x, t = threadIdx.x;     // block handles nodes 4b..4b+3
  if (b == 0) bn_sums[t] = 0.f;                  // 256 floats: sum[128], sum2[128]
  __shared__ float xs[4 * 128];
  xs[t] = x[(size_t)b * 512 + t];
  xs[t + 256] = x[(size_t)b * 512 + t + 256];
  __syncthreads();
  const int sel = t >> 7;                        // 0: W_proj/nproj, 1: W_skip/skip
  const float* W = sel ? W_skip : W_proj;        // wave-uniform
  const int c = t & 127;
  float acc0 = 0.f, acc1 = 0.f, acc2 = 0.f, acc3 = 0.f;
#pragma unroll 8
  for (int k = 0; k < 128; ++k) {
    const float w = W[k * 128 + c];
    acc0 = fmaf(xs[k], w, acc0);
    acc1 = fmaf(xs[128 + k], w, acc1);
    acc2 = fmaf(xs[256 + k], w, acc2);
    acc3 = fmaf(xs[384 + k], w, acc3);
  }
  float* dst = sel ? skip : nproj;
  dst[(size_t)(4 * b + 0) * 128 + c] = acc0;
  dst[(size_t)(4 * b + 1) * 128 + c] = acc1;
  dst[(size_t)(4 * b + 2) * 128 + c] = acc2;
  dst[(size_t)(4 * b + 3) * 128 + c] = acc3;
  if (sel == 0) {                                // logits from nproj accs
    const float as = a_src[c], at = a_tgt[c];
    const int h = c >> 5;
    float accs[4] = {acc0, acc1, acc2, acc3};
#pragma unroll
    for (int n = 0; n < 4; ++n) {
      float vs = accs[n] * as, vt = accs[n] * at;
#pragma unroll
      for (int off = 16; off; off >>= 1) {
        vs += __shfl_down(vs, off, 32);
        vt += __shfl_down(vt, off, 32);
      }
      if ((c & 31) == 0) {
        s_src[(4 * b + n) * 4 + h] = vs;
        s_tgt[(4 * b + n) * 4 + h] = vt;
      }
    }
  }
}

// ---------------- Kernel 2: sparse fused attention -----------------------
// One block (256 thr) per target row i. Masked entries are exactly 0 after
// softmax (exp(-1e9-max) underflows), so only conn==0 neighbors matter.
__global__ __launch_bounds__(256) void attn_kernel(
    const float* __restrict__ e,      // [N,N,32]
    const float* __restrict__ conn,   // [N,N]
    const float* __restrict__ W_edge, // [32,128]
    const float* __restrict__ b_edge, // [128]
    const float* __restrict__ a_edge, // [128]
    const float* __restrict__ s_src,  // [N,4]
    const float* __restrict__ s_tgt,  // [N,4]
    const float* __restrict__ nproj,  // [N,128]
    const float* __restrict__ skip,   // [N,128]
    float* __restrict__ out_pre)      // [N,128]
{
  const int i = blockIdx.x, t = threadIdx.x;
  __shared__ unsigned short nbr[NN];
  __shared__ float sc[MCAP * 4];          // scores -> attn weights, [n][h]
  __shared__ float ebuf[ETILE * 32];      // staged e-rows for current tile
  __shared__ float partial[256];
  __shared__ int cnt;

  const int c = t & 127;                  // output channel
  const int h = c >> 5;                   // head
  const int half = t >> 7;                // 0/1: edge-interleave group

  float Wc[DE_];                          // W_edge column c in registers
#pragma unroll
  for (int k = 0; k < DE_; ++k) Wc[k] = W_edge[k * 128 + c];
  const float aec = a_edge[c];
  const float bec = b_edge[c];
  const float ssi = s_src[i * 4 + h];

  if (t == 0) cnt = 0;
  __syncthreads();
  // --- compact live-neighbor list (order-free; only perturbs fp assoc.) ---
  {
    const float4 cv = ((const float4*)(conn + (size_t)i * NN))[t];
    const int jb = t << 2;
    if (cv.x > -0.5f) { int p = atomicAdd(&cnt, 1); nbr[p] = (unsigned short)(jb + 0); }
    if (cv.y > -0.5f) { int p = atomicAdd(&cnt, 1); nbr[p] = (unsigned short)(jb + 1); }
    if (cv.z > -0.5f) { int p = atomicAdd(&cnt, 1); nbr[p] = (unsigned short)(jb + 2); }
    if (cv.w > -0.5f) { int p = atomicAdd(&cnt, 1); nbr[p] = (unsigned short)(jb + 3); }
  }
  __syncthreads();
  const int M = min(cnt, MCAP);

  // --- phase A: per-edge scores, LDS-staged tiles -----------------------
  for (int base = 0; base < M; base += ETILE) {
    const int mT = min(ETILE, M - base);
    // cooperative stage: mT rows x 8 float4, all loads in flight at once
    for (int q = t; q < mT * 8; q += 256) {
      const int n = q >> 3, part = q & 7;
      const int j = nbr[base + n];
      ((float4*)ebuf)[q] =
          ((const float4*)(e + ((size_t)i << 15) + ((size_t)j << 5)))[part];
    }
    __syncthreads();
    for (int n = half; n < mT; n += 2) {
      const float4* eb4 = (const float4*)(ebuf + n * 32);  // wave-uniform addr
      float acc = bec;
#pragma unroll
      for (int q = 0; q < 8; ++q) {
        float4 v = eb4[q];
        acc = fmaf(v.x, Wc[4 * q + 0], acc);
        acc = fmaf(v.y, Wc[4 * q + 1], acc);
        acc = fmaf(v.z, Wc[4 * q + 2], acc);
        acc = fmaf(v.w, Wc[4 * q + 3], acc);
      }
      acc = acc > 0.f ? acc : SLOPE * acc;        // leaky on eproj
      float contrib = acc * aec;
#pragma unroll
      for (int off = 16; off; off >>= 1) contrib += __shfl_down(contrib, off, 32);
      if ((c & 31) == 0) {
        const int j = nbr[base + n];
        float sco = ssi + s_tgt[(size_t)j * 4 + h] + contrib;
        sco = sco > 0.f ? sco : SLOPE * sco;      // leaky on logits
        sc[(base + n) * 4 + h] = sco;
      }
    }
    __syncthreads();
  }

  // --- phase B: per-head softmax (one wave per head) --------------------
  {
    const int hh = t >> 6;
    const int lane = t & 63;
    float m = -1e30f;
    for (int n = lane; n < M; n += 64) m = fmaxf(m, sc[n * 4 + hh]);
#pragma unroll
    for (int off = 32; off; off >>= 1) m = fmaxf(m, __shfl_down(m, off, 64));
    m = __shfl(m, 0, 64);
    float s = 0.f;
    for (int n = lane; n < M; n += 64) s += __expf(sc[n * 4 + hh] - m);
#pragma unroll
    for (int off = 32; off; off >>= 1) s += __shfl_down(s, off, 64);
    s = __shfl(s, 0, 64);
    const float inv = 1.f / s;
    for (int n = lane; n < M; n += 64)
      sc[n * 4 + hh] = __expf(sc[n * 4 + hh] - m) * inv;
  }
  __syncthreads();

  // --- phase C: aggregate attn * nproj + skip ---------------------------
  float accum = 0.f;
  for (int n = half; n < M; n += 2) {
    const int j = nbr[n];
    accum = fmaf(sc[n * 4 + h], nproj[(size_t)j * 128 + c], accum);
  }
  partial[t] = accum;
  __syncthreads();
  if (t < 128) {
    float tot = partial[t] + partial[t + 128] + skip[(size_t)i * 128 + t];
    out_pre[(size_t)i * 128 + t] = tot;
  }
}

// ---------------- Kernel 3: BN stats (coalesced column reduction) ---------
// 32 blocks x 32 rows each. Coalesced float4 reads (one row = 512B per
// 32-lane group), LDS tree-reduce over 8 row-groups, then ONE atomicAdd per
// channel per block (32-deep contention total -- negligible, near-determin.)
__global__ __launch_bounds__(256) void bn_stats_kernel(
    const float* __restrict__ out_pre, float* __restrict__ bn_sums)
{
  const int b = blockIdx.x, t = threadIdx.x;
  const int rg = t >> 5, cg = t & 31;     // row-group 0..7, channel-group 0..31
  __shared__ float s_s[8][128], s_s2[8][128];
  float4 s = make_float4(0.f, 0.f, 0.f, 0.f);
  float4 s2 = make_float4(0.f, 0.f, 0.f, 0.f);
#pragma unroll
  for (int k = 0; k < 4; ++k) {
    const int r = b * 32 + k * 8 + rg;
    const float4 v = ((const float4*)(out_pre + (size_t)r * 128))[cg];
    s.x += v.x; s.y += v.y; s.z += v.z; s.w += v.w;
    s2.x += v.x * v.x; s2.y += v.y * v.y; s2.z += v.z * v.z; s2.w += v.w * v.w;
  }
  ((float4*)s_s[rg])[cg] = s;
  ((float4*)s_s2[rg])[cg] = s2;
  __syncthreads();
  if (t < 128) {
    float a = 0.f, a2 = 0.f;
#pragma unroll
    for (int g = 0; g < 8; ++g) { a += s_s[g][t]; a2 += s_s2[g][t]; }
    atomicAdd(bn_sums + t, a);
    atomicAdd(bn_sums + 128 + t, a2);
  }
}

// ---------------- Kernel 4: BN apply + bias + ELU (coalesced float4) ------
__global__ __launch_bounds__(256) void bn_apply_kernel(
    const float* __restrict__ out_pre, const float* __restrict__ bn_sums,
    const float* __restrict__ gamma, const float* __restrict__ beta,
    const float* __restrict__ bias, float* __restrict__ out)
{
  const int idx4 = blockIdx.x * 256 + threadIdx.x;   // 0..32767, = r*32 + c4/4
  const int c4 = (idx4 & 31) << 2;
  const float4 v = ((const float4*)out_pre)[idx4];
  const float r[4] = {v.x, v.y, v.z, v.w};
  float o[4];
#pragma unroll
  for (int k = 0; k < 4; ++k) {
    const int c = c4 + k;
    const float mu = bn_sums[c] * (1.f / 1024.f);
    const float var = bn_sums[128 + c] * (1.f / 1024.f) - mu * mu;
    const float rstd = rsqrtf(var + EPSV);
    const float g = gamma[c] * rstd;
    const float bb = beta[c] + bias[c] - mu * g;
    const float y = r[k] * g + bb;
    o[k] = y > 0.f ? y : expm1f(y);
  }
  ((float4*)out)[idx4] = make_float4(o[0], o[1], o[2], o[3]);
}

// ---------------- Launch ---------------------------------------------------
extern "C" void kernel_launch(void* const* d_in, const int* in_sizes, int n_in,
                              void* d_out, int out_size, void* d_ws,
                              size_t ws_size, hipStream_t stream)
{
  const float* x      = (const float*)d_in[0];
  const float* e      = (const float*)d_in[1];
  const float* conn   = (const float*)d_in[2];
  const float* W_proj = (const float*)d_in[3];
  const float* W_edge = (const float*)d_in[4];
  const float* b_edge = (const float*)d_in[5];
  const float* a_src  = (const float*)d_in[6];
  const float* a_tgt  = (const float*)d_in[7];
  const float* a_edge = (const float*)d_in[8];
  const float* W_skip = (const float*)d_in[9];
  const float* gamma  = (const float*)d_in[10];
  const float* beta   = (const float*)d_in[11];
  const float* bias   = (const float*)d_in[12];

  float* nproj   = (float*)d_ws;
  float* skip    = nproj + (size_t)NN * HF;
  float* out_pre = skip + (size_t)NN * HF;
  float* s_src   = out_pre + (size_t)NN * HF;
  float* s_tgt   = s_src + (size_t)NN * 4;
  float* bn_sums = s_tgt + (size_t)NN * 4;   // 256 floats: sum[128], sum2[128]

  proj_kernel<<<NN / 4, 256, 0, stream>>>(x, W_proj, W_skip, a_src, a_tgt,
                                          nproj, skip, s_src, s_tgt, bn_sums);
  attn_kernel<<<NN, 256, 0, stream>>>(e, conn, W_edge, b_edge, a_edge,
                                      s_src, s_tgt, nproj, skip, out_pre);
  bn_stats_kernel<<<32, 256, 0, stream>>>(out_pre, bn_sums);
  bn_apply_kernel<<<(NN * HF) / (256 * 4), 256, 0, stream>>>(
      out_pre, bn_sums, gamma, beta, bias, (float*)d_out);
}

// Round 4
// 227.783 us; speedup vs baseline: 1.0624x; 1.0214x over previous
//
#include <hip/hip_runtime.h>
#include <cstddef>

#define NN 1024
#define HF 128
#define DE_ 32
#define SLOPE 0.2f
#define EPSV 1e-5f
#define ETILE 64   // edges staged to LDS per tile in attn phase A
#define MCAP 320   // max live neighbors per row (dist: 51 +/- 7; 320 = 38 sigma)
#define NSLAB 32   // BN accumulator slabs; per-address atomic depth = NN/NSLAB = 32

// ---------------- Kernel 1: node projections (4 nodes/block) --------------
// Blocks 0..31 also zero the BN slab accumulators (stream-ordered vs attn).
__global__ __launch_bounds__(256) void proj_kernel(
    const float* __restrict__ x, const float* __restrict__ W_proj,
    const float* __restrict__ W_skip, const float* __restrict__ a_src,
    const float* __restrict__ a_tgt, float* __restrict__ nproj,
    float* __restrict__ skip, float* __restrict__ s_src,
    float* __restrict__ s_tgt, float* __restrict__ bn_part)
{
  const int b = blockIdx.x, t = threadIdx.x;     // block handles nodes 4b..4b+3
  if (b < NSLAB) bn_part[b * 256 + t] = 0.f;     // [NSLAB][256]: sum[128],sum2[128]
  __shared__ float xs[4 * 128];
  xs[t] = x[(size_t)b * 512 + t];
  xs[t + 256] = x[(size_t)b * 512 + t + 256];
  __syncthreads();
  const int sel = t >> 7;                        // 0: W_proj/nproj, 1: W_skip/skip
  const float* W = sel ? W_skip : W_proj;        // wave-uniform
  const int c = t & 127;
  float acc0 = 0.f, acc1 = 0.f, acc2 = 0.f, acc3 = 0.f;
#pragma unroll 8
  for (int k = 0; k < 128; ++k) {
    const float w = W[k * 128 + c];
    acc0 = fmaf(xs[k], w, acc0);
    acc1 = fmaf(xs[128 + k], w, acc1);
    acc2 = fmaf(xs[256 + k], w, acc2);
    acc3 = fmaf(xs[384 + k], w, acc3);
  }
  float* dst = sel ? skip : nproj;
  dst[(size_t)(4 * b + 0) * 128 + c] = acc0;
  dst[(size_t)(4 * b + 1) * 128 + c] = acc1;
  dst[(size_t)(4 * b + 2) * 128 + c] = acc2;
  dst[(size_t)(4 * b + 3) * 128 + c] = acc3;
  if (sel == 0) {                                // logits from nproj accs
    const float as = a_src[c], at = a_tgt[c];
    const int h = c >> 5;
    float accs[4] = {acc0, acc1, acc2, acc3};
#pragma unroll
    for (int n = 0; n < 4; ++n) {
      float vs = accs[n] * as, vt = accs[n] * at;
#pragma unroll
      for (int off = 16; off; off >>= 1) {
        vs += __shfl_down(vs, off, 32);
        vt += __shfl_down(vt, off, 32);
      }
      if ((c & 31) == 0) {
        s_src[(4 * b + n) * 4 + h] = vs;
        s_tgt[(4 * b + n) * 4 + h] = vt;
      }
    }
  }
}

// ---------------- Kernel 2: sparse fused attention -----------------------
// One block (256 thr) per target row i. Masked entries are exactly 0 after
// softmax (exp(-1e9-max) underflows), so only conn==0 neighbors matter.
// Epilogue feeds BN stats into slab (i&31): per-address atomic depth 32,
// proven free (R2: 32-deep atomics gave absmax 1.5e-5, no time cost).
__global__ __launch_bounds__(256) void attn_kernel(
    const float* __restrict__ e,      // [N,N,32]
    const float* __restrict__ conn,   // [N,N]
    const float* __restrict__ W_edge, // [32,128]
    const float* __restrict__ b_edge, // [128]
    const float* __restrict__ a_edge, // [128]
    const float* __restrict__ s_src,  // [N,4]
    const float* __restrict__ s_tgt,  // [N,4]
    const float* __restrict__ nproj,  // [N,128]
    const float* __restrict__ skip,   // [N,128]
    float* __restrict__ out_pre,      // [N,128]
    float* __restrict__ bn_part)      // [NSLAB][256]
{
  const int i = blockIdx.x, t = threadIdx.x;
  __shared__ unsigned short nbr[NN];
  __shared__ float sc[MCAP * 4];          // scores -> attn weights, [n][h]
  __shared__ float ebuf[ETILE * 32];      // staged e-rows for current tile
  __shared__ float partial[256];
  __shared__ int cnt;

  const int c = t & 127;                  // output channel
  const int h = c >> 5;                   // head
  const int half = t >> 7;                // 0/1: edge-interleave group

  float Wc[DE_];                          // W_edge column c in registers
#pragma unroll
  for (int k = 0; k < DE_; ++k) Wc[k] = W_edge[k * 128 + c];
  const float aec = a_edge[c];
  const float bec = b_edge[c];
  const float ssi = s_src[i * 4 + h];

  if (t == 0) cnt = 0;
  __syncthreads();
  // --- compact live-neighbor list (order-free; only perturbs fp assoc.) ---
  {
    const float4 cv = ((const float4*)(conn + (size_t)i * NN))[t];
    const int jb = t << 2;
    if (cv.x > -0.5f) { int p = atomicAdd(&cnt, 1); nbr[p] = (unsigned short)(jb + 0); }
    if (cv.y > -0.5f) { int p = atomicAdd(&cnt, 1); nbr[p] = (unsigned short)(jb + 1); }
    if (cv.z > -0.5f) { int p = atomicAdd(&cnt, 1); nbr[p] = (unsigned short)(jb + 2); }
    if (cv.w > -0.5f) { int p = atomicAdd(&cnt, 1); nbr[p] = (unsigned short)(jb + 3); }
  }
  __syncthreads();
  const int M = min(cnt, MCAP);

  // --- phase A: per-edge scores, LDS-staged tiles -----------------------
  for (int base = 0; base < M; base += ETILE) {
    const int mT = min(ETILE, M - base);
    // cooperative stage: mT rows x 8 float4, all loads in flight at once
    for (int q = t; q < mT * 8; q += 256) {
      const int n = q >> 3, part = q & 7;
      const int j = nbr[base + n];
      ((float4*)ebuf)[q] =
          ((const float4*)(e + ((size_t)i << 15) + ((size_t)j << 5)))[part];
    }
    __syncthreads();
    for (int n = half; n < mT; n += 2) {
      const float4* eb4 = (const float4*)(ebuf + n * 32);  // wave-uniform addr
      float acc = bec;
#pragma unroll
      for (int q = 0; q < 8; ++q) {
        float4 v = eb4[q];
        acc = fmaf(v.x, Wc[4 * q + 0], acc);
        acc = fmaf(v.y, Wc[4 * q + 1], acc);
        acc = fmaf(v.z, Wc[4 * q + 2], acc);
        acc = fmaf(v.w, Wc[4 * q + 3], acc);
      }
      acc = acc > 0.f ? acc : SLOPE * acc;        // leaky on eproj
      float contrib = acc * aec;
#pragma unroll
      for (int off = 16; off; off >>= 1) contrib += __shfl_down(contrib, off, 32);
      if ((c & 31) == 0) {
        const int j = nbr[base + n];
        float sco = ssi + s_tgt[(size_t)j * 4 + h] + contrib;
        sco = sco > 0.f ? sco : SLOPE * sco;      // leaky on logits
        sc[(base + n) * 4 + h] = sco;
      }
    }
    __syncthreads();
  }

  // --- phase B: per-head softmax (one wave per head) --------------------
  {
    const int hh = t >> 6;
    const int lane = t & 63;
    float m = -1e30f;
    for (int n = lane; n < M; n += 64) m = fmaxf(m, sc[n * 4 + hh]);
#pragma unroll
    for (int off = 32; off; off >>= 1) m = fmaxf(m, __shfl_down(m, off, 64));
    m = __shfl(m, 0, 64);
    float s = 0.f;
    for (int n = lane; n < M; n += 64) s += __expf(sc[n * 4 + hh] - m);
#pragma unroll
    for (int off = 32; off; off >>= 1) s += __shfl_down(s, off, 64);
    s = __shfl(s, 0, 64);
    const float inv = 1.f / s;
    for (int n = lane; n < M; n += 64)
      sc[n * 4 + hh] = __expf(sc[n * 4 + hh] - m) * inv;
  }
  __syncthreads();

  // --- phase C: aggregate attn * nproj + skip (4-edge batched gathers) --
  float accum = 0.f;
  int n = half;
  for (; n + 6 < M; n += 8) {                   // 4 edges per half-group iter
    const int j0 = nbr[n], j1 = nbr[n + 2], j2 = nbr[n + 4], j3 = nbr[n + 6];
    const float w0 = sc[n * 4 + h],       w1 = sc[(n + 2) * 4 + h];
    const float w2 = sc[(n + 4) * 4 + h], w3 = sc[(n + 6) * 4 + h];
    const float v0 = nproj[(size_t)j0 * 128 + c];
    const float v1 = nproj[(size_t)j1 * 128 + c];
    const float v2 = nproj[(size_t)j2 * 128 + c];
    const float v3 = nproj[(size_t)j3 * 128 + c];
    accum = fmaf(w0, v0, accum);
    accum = fmaf(w1, v1, accum);
    accum = fmaf(w2, v2, accum);
    accum = fmaf(w3, v3, accum);
  }
  for (; n < M; n += 2)
    accum = fmaf(sc[n * 4 + h], nproj[(size_t)nbr[n] * 128 + c], accum);
  partial[t] = accum;
  __syncthreads();
  if (t < 128) {
    float tot = partial[t] + partial[t + 128] + skip[(size_t)i * 128 + t];
    out_pre[(size_t)i * 128 + t] = tot;
    float* slab = bn_part + (i & (NSLAB - 1)) * 256;
    atomicAdd(slab + t, tot);                   // depth-32 per address: free
    atomicAdd(slab + 128 + t, tot * tot);
  }
}

// ---------------- Kernel 3: BN finalize + apply + bias + ELU --------------
// Prologue: every block redundantly reduces the 32 slabs (coalesced, 32KB
// from L2) -> per-channel scale/shift in LDS. Main: coalesced float4 apply.
__global__ __launch_bounds__(256) void bn_apply_kernel(
    const float* __restrict__ out_pre, const float* __restrict__ bn_part,
    const float* __restrict__ gamma, const float* __restrict__ beta,
    const float* __restrict__ bias, float* __restrict__ out)
{
  const int t = threadIdx.x;
  __shared__ float red[256];
  __shared__ float stat_g[128], stat_b[128];
  float a = 0.f;
#pragma unroll
  for (int g = 0; g < NSLAB; ++g) a += bn_part[g * 256 + t];
  red[t] = a;
  __syncthreads();
  if (t < 128) {
    const float mu = red[t] * (1.f / 1024.f);
    const float var = red[128 + t] * (1.f / 1024.f) - mu * mu;
    const float rstd = rsqrtf(var + EPSV);
    const float g = gamma[t] * rstd;
    stat_g[t] = g;
    stat_b[t] = beta[t] + bias[t] - mu * g;
  }
  __syncthreads();

  const int idx4 = blockIdx.x * 256 + t;             // 0..32767, = r*32 + c4/4
  const int c4 = (idx4 & 31) << 2;
  const float4 v = ((const float4*)out_pre)[idx4];
  const float r[4] = {v.x, v.y, v.z, v.w};
  float o[4];
#pragma unroll
  for (int k = 0; k < 4; ++k) {
    const float y = r[k] * stat_g[c4 + k] + stat_b[c4 + k];
    o[k] = y > 0.f ? y : expm1f(y);
  }
  ((float4*)out)[idx4] = make_float4(o[0], o[1], o[2], o[3]);
}

// ---------------- Launch ---------------------------------------------------
extern "C" void kernel_launch(void* const* d_in, const int* in_sizes, int n_in,
                              void* d_out, int out_size, void* d_ws,
                              size_t ws_size, hipStream_t stream)
{
  const float* x      = (const float*)d_in[0];
  const float* e      = (const float*)d_in[1];
  const float* conn   = (const float*)d_in[2];
  const float* W_proj = (const float*)d_in[3];
  const float* W_edge = (const float*)d_in[4];
  const float* b_edge = (const float*)d_in[5];
  const float* a_src  = (const float*)d_in[6];
  const float* a_tgt  = (const float*)d_in[7];
  const float* a_edge = (const float*)d_in[8];
  const float* W_skip = (const float*)d_in[9];
  const float* gamma  = (const float*)d_in[10];
  const float* beta   = (const float*)d_in[11];
  const float* bias   = (const float*)d_in[12];

  float* nproj   = (float*)d_ws;
  float* skip    = nproj + (size_t)NN * HF;
  float* out_pre = skip + (size_t)NN * HF;
  float* s_src   = out_pre + (size_t)NN * HF;
  float* s_tgt   = s_src + (size_t)NN * 4;
  float* bn_part = s_tgt + (size_t)NN * 4;   // [NSLAB][256]

  proj_kernel<<<NN / 4, 256, 0, stream>>>(x, W_proj, W_skip, a_src, a_tgt,
                                          nproj, skip, s_src, s_tgt, bn_part);
  attn_kernel<<<NN, 256, 0, stream>>>(e, conn, W_edge, b_edge, a_edge,
                                      s_src, s_tgt, nproj, skip, out_pre,
                                      bn_part);
  bn_apply_kernel<<<(NN * HF) / (256 * 4), 256, 0, stream>>>(
      out_pre, bn_part, gamma, beta, bias, (float*)d_out);
}